// Round 6
// baseline (99.071 us; speedup 1.0000x reference)
//
#include <hip/hip_runtime.h>
#include <math.h>

#define CC 144
#define WW 77
#define KW 10
#define FC 64
#define CONV_OUT 68                 // WW-KW+1
#define H2 128
#define CONCAT (CC*FC + CONV_OUT)   // 9284
#define NCONVBLK 4
#define NCH (CC/NCONVBLK)           // 36 channels per conv block
#define NBLK (CC + NCONVBLK)        // 148
#define POISON 0xAAAAAAAAu          // harness ws poison pattern

// Single fused kernel, fence-free cross-XCD handoff:
//  - partial[] stores are agent-scope relaxed (__hip_atomic_store ->
//    global_store sc0 sc1: write-through past the non-coherent per-XCD L2,
//    visible in L3). NO __threadfence / buffer_wbl2 anywhere (R3's -14us bug).
//  - hand-rolled release: s_waitcnt vmcnt(0) before the relaxed counter bump
//    guarantees this block's write-through stores reached L3 first.
//  - last-arriving block reads partials with agent-scope relaxed loads
//    (bypass its own L1/L2) and runs the finale.
__global__ __launch_bounds__(256, 1) void fused_kernel(
    const float* __restrict__ x,      // [CC,WW]
    const float* __restrict__ fc_w,   // [CC,FC,WW]
    const float* __restrict__ fc_b,   // [CC,FC]
    const float* __restrict__ conv_w, // [CC,KW]
    const float* __restrict__ conv_b, // [1]
    const float* __restrict__ w2,     // [H2, CONCAT]
    const float* __restrict__ b2,     // [H2]
    const float* __restrict__ w3,     // [H2]
    const float* __restrict__ b3,     // [1]
    float* __restrict__ out,          // [1]
    float* __restrict__ partial,      // ws: [NBLK, H2]
    unsigned int* __restrict__ counter) // ws: poison-initialized (0xAAAAAAAA)
{
    __shared__ float xpart[NCH*WW];   // conv blocks only (~11 KB)
    __shared__ float cwp[NCH*KW];
    __shared__ float vals[CONV_OUT];  // fc outs (64) or conv outs (68)
    __shared__ float red2[2][H2];
    __shared__ float red[2];
    __shared__ unsigned int last_flag;

    const int t = threadIdx.x;
    const int blk = blockIdx.x;
    const int j = t >> 1, p = t & 1;  // W2 phase: 2 lanes per output row

    if (blk < CC) {
        const int c = blk;
        // Issue this lane's 32-float w2 slice FIRST so its latency overlaps
        // the fc_w loads below (no barrier in between; x comes via L1/L3).
        float4 wreg[8];
        const float4* wv = (const float4*)(w2 + (size_t)j*CONCAT + c*FC + p*32);
        #pragma unroll
        for (int i = 0; i < 8; ++i) wreg[i] = wv[i];

        // fc_out[c,d] = dot(fc_w[c,d,:], x[c,:]) + fc_b[c,d]; 4 lanes per d.
        // Fully unrolled: all ~20 loads in flight together.
        {
            const int d = t >> 2, p4 = t & 3;
            const float* wrow = fc_w + (size_t)(c*FC + d)*WW;
            const float* xr = x + c*WW;
            const float bias = fc_b[c*FC + d];
            float s = 0.f;
            #pragma unroll
            for (int i = 0; i < 19; ++i) {       // w = p4 + 4i <= 75
                const int w = p4 + 4*i;
                s += wrow[w] * xr[w];
            }
            if (p4 == 0) s += wrow[76] * xr[76]; // tail (77 = 19*4 + 1)
            s += __shfl_down(s, 2, 4);
            s += __shfl_down(s, 1, 4);
            if (p4 == 0) vals[d] = s + bias;
        }
        __syncthreads();
        // partial[c][j] = dot(w2[j, c*64:(c+1)*64], fc_out[c,:])
        {
            const float* vp = vals + p*32;
            float s = 0.f;
            #pragma unroll
            for (int i = 0; i < 8; ++i) {
                float4 w4 = wreg[i];
                s += w4.x*vp[4*i] + w4.y*vp[4*i+1] + w4.z*vp[4*i+2] + w4.w*vp[4*i+3];
            }
            s += __shfl_down(s, 1, 2);
            if (p == 0)
                __hip_atomic_store(partial + (size_t)blk*H2 + j, s,
                                   __ATOMIC_RELAXED, __HIP_MEMORY_SCOPE_AGENT);
        }
    } else {
        // conv partial over channels [c0, c0+NCH)
        const int cidx = blk - CC;
        const int c0 = cidx * NCH;
        for (int i = t; i < NCH*WW; i += 256) xpart[i] = x[c0*WW + i];
        for (int i = t; i < NCH*KW; i += 256) cwp[i] = conv_w[c0*KW + i];
        __syncthreads();
        if (t < CONV_OUT*2) {
            const int jj = t >> 1, pc = t & 1;
            float s = 0.f;
            for (int ci = pc; ci < NCH; ci += 2) {
                const float* xr = xpart + ci*WW + jj;
                const float* wr = cwp + ci*KW;
                #pragma unroll
                for (int k = 0; k < KW; ++k) s += xr[k] * wr[k];
            }
            s += __shfl_down(s, 1, 2);
            if (pc == 0) vals[jj] = s + (cidx == 0 ? conv_b[0] : 0.f);
        }
        __syncthreads();
        // partial[blk][j] = dot(w2[j, 9216:9284], conv_part[:])
        {
            const float* vp = vals + p*34;
            const float* wrow = w2 + (size_t)j*CONCAT + CC*FC + p*34;
            float s = 0.f;
            #pragma unroll
            for (int i = 0; i < 34; ++i) s += wrow[i] * vp[i];
            s += __shfl_down(s, 1, 2);
            if (p == 0)
                __hip_atomic_store(partial + (size_t)blk*H2 + j, s,
                                   __ATOMIC_RELAXED, __HIP_MEMORY_SCOPE_AGENT);
        }
    }

    // Hand-rolled release: drain this wave's write-through stores to L3,
    // then bump the arrival counter (relaxed, L3-coherent). No wbl2/inv.
    asm volatile("s_waitcnt vmcnt(0)" ::: "memory");
    __syncthreads();
    if (t == 0) {
        unsigned int old = __hip_atomic_fetch_add(counter, 1u,
                               __ATOMIC_RELAXED, __HIP_MEMORY_SCOPE_AGENT);
        last_flag = ((old - POISON) % (unsigned)NBLK == (unsigned)(NBLK - 1)) ? 1u : 0u;
    }
    __syncthreads();

    if (last_flag) {
        // Finale in the last-arriving block. Agent-scope loads bypass this
        // XCD's L1/L2 and read the partials from L3.
        const int half = t >> 7, jj = t & 127;   // 2 groups x 128 lanes
        float s = 0.f;
        for (int b = half; b < NBLK; b += 2)
            s += __hip_atomic_load(partial + (size_t)b*H2 + jj,
                                   __ATOMIC_RELAXED, __HIP_MEMORY_SCOPE_AGENT);
        red2[half][jj] = s;
        __syncthreads();
        if (t < H2) {
            float h = fmaxf(b2[t] + red2[0][t] + red2[1][t], 0.f);
            float v = h * w3[t];
            #pragma unroll
            for (int off = 32; off > 0; off >>= 1) v += __shfl_down(v, off, 64);
            if ((t & 63) == 0) red[t >> 6] = v;
        }
        __syncthreads();
        if (t == 0) {
            float r = fmaxf(red[0] + red[1] + b3[0], 0.f);
            out[0] = 1.0f / (1.0f + expf(-r));
        }
    }
}

extern "C" void kernel_launch(void* const* d_in, const int* in_sizes, int n_in,
                              void* d_out, int out_size, void* d_ws, size_t ws_size,
                              hipStream_t stream) {
    const float* x      = (const float*)d_in[0];
    const float* fc_w   = (const float*)d_in[1];
    const float* fc_b   = (const float*)d_in[2];
    const float* conv_w = (const float*)d_in[3];
    const float* conv_b = (const float*)d_in[4];
    const float* w2     = (const float*)d_in[5];
    const float* b2     = (const float*)d_in[6];
    const float* w3     = (const float*)d_in[7];
    const float* b3     = (const float*)d_in[8];
    float* out = (float*)d_out;

    float* partial = (float*)d_ws;                       // [NBLK*H2] floats
    unsigned int* counter =
        (unsigned int*)((char*)d_ws + (size_t)NBLK*H2*sizeof(float));

    fused_kernel<<<NBLK, 256, 0, stream>>>(
        x, fc_w, fc_b, conv_w, conv_b, w2, b2, w3, b3, out, partial, counter);
}

// Round 7
// 84.208 us; speedup vs baseline: 1.1765x; 1.1765x over previous
//
#include <hip/hip_runtime.h>
#include <math.h>

#define CC 144
#define WW 77
#define KW 10
#define FC 64
#define CONV_OUT 68                 // WW-KW+1
#define H2 128
#define CONCAT (CC*FC + CONV_OUT)   // 9284
#define NCONVBLK 4
#define NCH (CC/NCONVBLK)           // 36 channels per conv block
#define NBLK (CC + NCONVBLK)        // 148

// Kernel 1: blocks 0..143 -> per-channel FC + its 64-wide W2 slice;
// blocks 144..147 -> quarter of conv channels + the 68-wide W2 slice
// (conv is linear into h, so channel-partial conv sums are additive).
// Each block writes a disjoint 128-float partial: no atomics, no fences;
// the kernel boundary provides cross-XCD coherence.
// NOTE (R3/R6 post-mortems): single-kernel fusion with cross-XCD handoff
// costs ~+14us on gfx950 whether done with __threadfence (wbl2/inv) or
// write-through agent-scope atomics — the kernel boundary is cheaper.
__global__ __launch_bounds__(256, 1) void partials_kernel(
    const float* __restrict__ x,      // [CC,WW]
    const float* __restrict__ fc_w,   // [CC,FC,WW]
    const float* __restrict__ fc_b,   // [CC,FC]
    const float* __restrict__ conv_w, // [CC,KW]
    const float* __restrict__ conv_b, // [1]
    const float* __restrict__ w2,     // [H2, CONCAT]
    float* __restrict__ partial)      // ws: [NBLK, H2]
{
    __shared__ float xpart[NCH*WW];   // conv blocks only (~11 KB)
    __shared__ float cwp[NCH*KW];
    __shared__ float vals[CONV_OUT];  // fc outs (64) or conv outs (68)

    const int t = threadIdx.x;
    const int blk = blockIdx.x;
    const int j = t >> 1, p = t & 1;  // W2 phase: 2 lanes per output row

    if (blk < CC) {
        const int c = blk;
        // Issue this lane's 32-float w2 slice FIRST so its latency overlaps
        // the fc_w loads below (no barrier in between; x comes via L1/L3).
        float4 wreg[8];
        const float4* wv = (const float4*)(w2 + (size_t)j*CONCAT + c*FC + p*32);
        #pragma unroll
        for (int i = 0; i < 8; ++i) wreg[i] = wv[i];

        // fc_out[c,d] = dot(fc_w[c,d,:], x[c,:]) + fc_b[c,d]; 4 lanes per d.
        // Fully unrolled so all ~20 loads are in flight together (one latency,
        // not a serialized load-use chain).
        {
            const int d = t >> 2, p4 = t & 3;
            const float* wrow = fc_w + (size_t)(c*FC + d)*WW;
            const float* xr = x + c*WW;
            const float bias = fc_b[c*FC + d];   // hoisted: overlaps with dot
            float s = 0.f;
            #pragma unroll
            for (int i = 0; i < 19; ++i) {       // w = p4 + 4i <= 75, in range
                const int w = p4 + 4*i;
                s += wrow[w] * xr[w];
            }
            if (p4 == 0) s += wrow[76] * xr[76]; // tail (77 = 19*4 + 1)
            s += __shfl_down(s, 2, 4);
            s += __shfl_down(s, 1, 4);
            if (p4 == 0) vals[d] = s + bias;
        }
        __syncthreads();
        // partial[c][j] = dot(w2[j, c*64 : (c+1)*64], fc_out[c,:])
        {
            const float* vp = vals + p*32;
            float s = 0.f;
            #pragma unroll
            for (int i = 0; i < 8; ++i) {
                float4 w4 = wreg[i];
                s += w4.x*vp[4*i] + w4.y*vp[4*i+1] + w4.z*vp[4*i+2] + w4.w*vp[4*i+3];
            }
            s += __shfl_down(s, 1, 2);
            if (p == 0) partial[(size_t)blk*H2 + j] = s;
        }
    } else {
        // conv partial over channels [c0, c0+NCH)
        const int cidx = blk - CC;
        const int c0 = cidx * NCH;
        for (int i = t; i < NCH*WW; i += 256) xpart[i] = x[c0*WW + i];
        for (int i = t; i < NCH*KW; i += 256) cwp[i] = conv_w[c0*KW + i];
        __syncthreads();
        if (t < CONV_OUT*2) {
            const int jj = t >> 1, pc = t & 1;
            float s = 0.f;
            for (int ci = pc; ci < NCH; ci += 2) {
                const float* xr = xpart + ci*WW + jj;
                const float* wr = cwp + ci*KW;
                #pragma unroll
                for (int k = 0; k < KW; ++k) s += xr[k] * wr[k];
            }
            s += __shfl_down(s, 1, 2);
            if (pc == 0) vals[jj] = s + (cidx == 0 ? conv_b[0] : 0.f);
        }
        __syncthreads();
        // partial[blk][j] = dot(w2[j, 9216 : 9284], conv_part[:])
        {
            const float* vp = vals + p*34;
            const float* wrow = w2 + (size_t)j*CONCAT + CC*FC + p*34;
            float s = 0.f;
            #pragma unroll
            for (int i = 0; i < 34; ++i) s += wrow[i] * vp[i];
            s += __shfl_down(s, 1, 2);
            if (p == 0) partial[(size_t)blk*H2 + j] = s;
        }
    }
}

// Kernel 2: reduce NBLK partials with float4 loads (16 coalesced row-groups),
// bias+relu, w3 dot, relu+sigmoid.
__global__ __launch_bounds__(512, 1) void finale_kernel(
    const float* __restrict__ partial, // [NBLK, H2]
    const float* __restrict__ b2,      // [H2]
    const float* __restrict__ w3,      // [H2]
    const float* __restrict__ b3,      // [1]
    float* __restrict__ out)           // [1]
{
    __shared__ float red2[16][H2];     // 8 KB
    __shared__ float red[2];
    const int t = threadIdx.x;
    const int g  = t >> 5;             // 16 groups of 32 threads
    const int c4 = t & 31;             // float4 index within a 128-float row

    const float4* p4 = (const float4*)partial;
    float4 s4 = make_float4(0.f, 0.f, 0.f, 0.f);
    for (int b = g; b < NBLK; b += 16) {   // each iter: 2 fully-coalesced rows/wave
        float4 v = p4[(size_t)b*32 + c4];
        s4.x += v.x; s4.y += v.y; s4.z += v.z; s4.w += v.w;
    }
    red2[g][c4*4+0] = s4.x;
    red2[g][c4*4+1] = s4.y;
    red2[g][c4*4+2] = s4.z;
    red2[g][c4*4+3] = s4.w;
    __syncthreads();

    if (t < H2) {
        float h = b2[t];
        #pragma unroll
        for (int gg = 0; gg < 16; ++gg) h += red2[gg][t];
        h = fmaxf(h, 0.f);
        float v = h * w3[t];
        #pragma unroll
        for (int off = 32; off > 0; off >>= 1) v += __shfl_down(v, off, 64);
        if ((t & 63) == 0) red[t >> 6] = v;
    }
    __syncthreads();
    if (t == 0) {
        float r = fmaxf(red[0] + red[1] + b3[0], 0.f);
        out[0] = 1.0f / (1.0f + expf(-r));
    }
}

extern "C" void kernel_launch(void* const* d_in, const int* in_sizes, int n_in,
                              void* d_out, int out_size, void* d_ws, size_t ws_size,
                              hipStream_t stream) {
    const float* x      = (const float*)d_in[0];
    const float* fc_w   = (const float*)d_in[1];
    const float* fc_b   = (const float*)d_in[2];
    const float* conv_w = (const float*)d_in[3];
    const float* conv_b = (const float*)d_in[4];
    const float* w2     = (const float*)d_in[5];
    const float* b2     = (const float*)d_in[6];
    const float* w3     = (const float*)d_in[7];
    const float* b3     = (const float*)d_in[8];
    float* out = (float*)d_out;

    float* partial = (float*)d_ws;    // [NBLK*H2] floats, fully overwritten

    partials_kernel<<<NBLK, 256, 0, stream>>>(
        x, fc_w, fc_b, conv_w, conv_b, w2, partial);
    finale_kernel<<<1, 512, 0, stream>>>(partial, b2, w3, b3, out);
}